// Round 1
// baseline (651.060 us; speedup 1.0000x reference)
//
#include <hip/hip_runtime.h>
#include <hip/hip_bf16.h>
#include <math.h>

#define NNODES 50000
#define NEDGES 500000
#define ETOT   (NEDGES + NNODES)
#define DIN    128
#define CH     256
#define SLOPE  0.2f

static __device__ __forceinline__ float wave_reduce_max(float v) {
#pragma unroll
  for (int off = 32; off > 0; off >>= 1) v = fmaxf(v, __shfl_xor(v, off));
  return v;
}
static __device__ __forceinline__ float wave_reduce_sum(float v) {
#pragma unroll
  for (int off = 32; off > 0; off >>= 1) v += __shfl_xor(v, off);
  return v;
}

// ---------------- CSR build (dst-sorted) ----------------
__global__ void degree_kernel(const int* __restrict__ ei, int* __restrict__ deg) {
  int e = blockIdx.x * blockDim.x + threadIdx.x;
  if (e >= ETOT) return;
  int dst = (e < NEDGES) ? ei[NEDGES + e] : (e - NEDGES);
  atomicAdd(&deg[dst], 1);
}

__global__ void scan_kernel(const int* __restrict__ deg, int* __restrict__ rowptr,
                            int* __restrict__ cursor) {
  __shared__ int buf[1024];
  __shared__ int carry_s;
  int tid = threadIdx.x;
  if (tid == 0) carry_s = 0;
  __syncthreads();
  for (int base = 0; base < NNODES; base += 1024) {
    int i = base + tid;
    int v = (i < NNODES) ? deg[i] : 0;
    buf[tid] = v;
    __syncthreads();
    for (int off = 1; off < 1024; off <<= 1) {
      int t = (tid >= off) ? buf[tid - off] : 0;
      __syncthreads();
      buf[tid] += t;
      __syncthreads();
    }
    int incl  = buf[tid];
    int total = buf[1023];
    int carry = carry_s;
    int excl  = carry + incl - v;
    if (i < NNODES) { rowptr[i] = excl; cursor[i] = excl; }
    __syncthreads();
    if (tid == 0) carry_s = carry + total;
    __syncthreads();
  }
  if (tid == 0) rowptr[NNODES] = carry_s;
}

__global__ void scatter_kernel(const int* __restrict__ ei, int* __restrict__ cursor,
                               int* __restrict__ csr_src) {
  int e = blockIdx.x * blockDim.x + threadIdx.x;
  if (e >= ETOT) return;
  int src, dst;
  if (e < NEDGES) { src = ei[e]; dst = ei[NEDGES + e]; }
  else            { src = e - NEDGES; dst = src; }
  int slot = atomicAdd(&cursor[dst], 1);
  csr_src[slot] = src;
}

// ---------------- fp32 GEMM: H[m][c] = sum_k X[m][k] * W[c][k] ----------------
#define BM 64
#define BN 64
#define BK 16

__global__ __launch_bounds__(256) void gemm_xwt(const float* __restrict__ X, int ldx,
                                                const float* __restrict__ W, int K,
                                                float* __restrict__ Hout, int M) {
  __shared__ float As[BK][BM + 1];
  __shared__ float Bs[BK][BN + 1];
  int bm = blockIdx.y * BM;
  int bn = blockIdx.x * BN;
  int tid = threadIdx.x;
  int trow = (tid / 16) * 4;
  int tcol = (tid % 16) * 4;
  int lr = tid >> 2;         // 0..63 : row within tile
  int lk = (tid & 3) * 4;    // 0,4,8,12 : k offset
  float acc[4][4] = {};
  for (int k0 = 0; k0 < K; k0 += BK) {
    float4 av = make_float4(0.f, 0.f, 0.f, 0.f);
    int gm = bm + lr;
    if (gm < M) av = *(const float4*)(X + (size_t)gm * ldx + k0 + lk);
    As[lk + 0][lr] = av.x; As[lk + 1][lr] = av.y;
    As[lk + 2][lr] = av.z; As[lk + 3][lr] = av.w;
    float4 bv = *(const float4*)(W + (size_t)(bn + lr) * K + k0 + lk);
    Bs[lk + 0][lr] = bv.x; Bs[lk + 1][lr] = bv.y;
    Bs[lk + 2][lr] = bv.z; Bs[lk + 3][lr] = bv.w;
    __syncthreads();
#pragma unroll
    for (int k = 0; k < BK; k++) {
      float a[4], b[4];
#pragma unroll
      for (int i = 0; i < 4; i++) a[i] = As[k][trow + i];
#pragma unroll
      for (int j = 0; j < 4; j++) b[j] = Bs[k][tcol + j];
#pragma unroll
      for (int i = 0; i < 4; i++)
#pragma unroll
        for (int j = 0; j < 4; j++) acc[i][j] += a[i] * b[j];
    }
    __syncthreads();
  }
#pragma unroll
  for (int i = 0; i < 4; i++) {
    int gm = bm + trow + i;
    if (gm < M) {
      float4 o = make_float4(acc[i][0], acc[i][1], acc[i][2], acc[i][3]);
      *(float4*)(Hout + (size_t)gm * CH + bn + tcol) = o;
    }
  }
}

// ---------------- per-node attention scores ----------------
__global__ __launch_bounds__(64) void score_kernel(const float* __restrict__ Hm,
                                                   const float* __restrict__ a_src,
                                                   const float* __restrict__ a_dst,
                                                   float* __restrict__ eS,
                                                   float* __restrict__ eD) {
  int n = blockIdx.x;
  int lane = threadIdx.x;
  float4 h  = *(const float4*)(Hm + (size_t)n * CH + lane * 4);
  float4 as = *(const float4*)(a_src + lane * 4);
  float4 ad = *(const float4*)(a_dst + lane * 4);
  float s = h.x * as.x + h.y * as.y + h.z * as.z + h.w * as.w;
  float d = h.x * ad.x + h.y * ad.y + h.z * ad.z + h.w * ad.w;
  s = wave_reduce_sum(s);
  d = wave_reduce_sum(d);
  if (lane == 0) { eS[n] = s; eD[n] = d; }
}

// ---------------- per-node softmax + aggregate (+bias, +ReLU) ----------------
__global__ __launch_bounds__(64) void aggregate_kernel(
    const float* __restrict__ Hm, const float* __restrict__ eS,
    const float* __restrict__ eD, const int* __restrict__ rowptr,
    const int* __restrict__ csr_src, const float* __restrict__ bias,
    float* __restrict__ out, int outOffset) {
  int n = blockIdx.x;
  int lane = threadIdx.x;
  int beg = rowptr[n], end = rowptr[n + 1];
  float ed = eD[n];

  float m = -1e30f;
  for (int k = beg + lane; k < end; k += 64) {
    float e = eS[csr_src[k]] + ed;
    e = (e >= 0.f) ? e : SLOPE * e;
    m = fmaxf(m, e);
  }
  m = wave_reduce_max(m);

  float dsum = 0.f;
  for (int k = beg + lane; k < end; k += 64) {
    float e = eS[csr_src[k]] + ed;
    e = (e >= 0.f) ? e : SLOPE * e;
    dsum += __expf(e - m);
  }
  dsum = wave_reduce_sum(dsum) + 1e-16f;
  float inv = 1.f / dsum;

  float4 acc = make_float4(0.f, 0.f, 0.f, 0.f);
  for (int k = beg; k < end; k++) {
    int s = csr_src[k];
    float e = eS[s] + ed;
    e = (e >= 0.f) ? e : SLOPE * e;
    float alpha = __expf(e - m) * inv;
    float4 h = *(const float4*)(Hm + (size_t)s * CH + lane * 4);
    acc.x += alpha * h.x; acc.y += alpha * h.y;
    acc.z += alpha * h.z; acc.w += alpha * h.w;
  }
  float4 b = *(const float4*)(bias + lane * 4);
  float4 o;
  o.x = fmaxf(acc.x + b.x, 0.f);
  o.y = fmaxf(acc.y + b.y, 0.f);
  o.z = fmaxf(acc.z + b.z, 0.f);
  o.w = fmaxf(acc.w + b.w, 0.f);
  *(float4*)(out + (size_t)n * 512 + outOffset + lane * 4) = o;
}

extern "C" void kernel_launch(void* const* d_in, const int* in_sizes, int n_in,
                              void* d_out, int out_size, void* d_ws, size_t ws_size,
                              hipStream_t stream) {
  const float* x   = (const float*)d_in[0];
  const int*   ei  = (const int*)d_in[1];
  const float* W1  = (const float*)d_in[2];
  const float* a1s = (const float*)d_in[3];
  const float* a1d = (const float*)d_in[4];
  const float* b1  = (const float*)d_in[5];
  const float* W2  = (const float*)d_in[6];
  const float* a2s = (const float*)d_in[7];
  const float* a2d = (const float*)d_in[8];
  const float* b2  = (const float*)d_in[9];
  float* out = (float*)d_out;

  char* ws = (char*)d_ws;
  size_t off = 0;
  auto alloc = [&](size_t bytes) -> void* {
    void* p = ws + off;
    off = (off + bytes + 255) & ~(size_t)255;
    return p;
  };
  float* Hm     = (float*)alloc(sizeof(float) * (size_t)NNODES * CH);
  float* eS     = (float*)alloc(sizeof(float) * NNODES);
  float* eD     = (float*)alloc(sizeof(float) * NNODES);
  int*   rowptr = (int*)alloc(sizeof(int) * (NNODES + 1));
  int*   cursor = (int*)alloc(sizeof(int) * NNODES);
  int*   csrsrc = (int*)alloc(sizeof(int) * ETOT);
  int*   deg    = (int*)alloc(sizeof(int) * NNODES);

  // CSR build (edge list identical for both layers)
  hipMemsetAsync(deg, 0, sizeof(int) * NNODES, stream);
  degree_kernel<<<(ETOT + 255) / 256, 256, 0, stream>>>(ei, deg);
  scan_kernel<<<1, 1024, 0, stream>>>(deg, rowptr, cursor);
  scatter_kernel<<<(ETOT + 255) / 256, 256, 0, stream>>>(ei, cursor, csrsrc);

  dim3 gemm_grid(CH / BN, (NNODES + BM - 1) / BM);

  // ---- layer 1 ----
  gemm_xwt<<<gemm_grid, 256, 0, stream>>>(x, DIN, W1, DIN, Hm, NNODES);
  score_kernel<<<NNODES, 64, 0, stream>>>(Hm, a1s, a1d, eS, eD);
  aggregate_kernel<<<NNODES, 64, 0, stream>>>(Hm, eS, eD, rowptr, csrsrc, b1, out, 0);

  // ---- layer 2 (reads x1 from d_out cols [0,256), stride 512) ----
  gemm_xwt<<<gemm_grid, 256, 0, stream>>>(out, 512, W2, CH, Hm, NNODES);
  score_kernel<<<NNODES, 64, 0, stream>>>(Hm, a2s, a2d, eS, eD);
  aggregate_kernel<<<NNODES, 64, 0, stream>>>(Hm, eS, eD, rowptr, csrsrc, b2, out, 256);
}

// Round 2
// 519.402 us; speedup vs baseline: 1.2535x; 1.2535x over previous
//
#include <hip/hip_runtime.h>
#include <hip/hip_bf16.h>
#include <math.h>

#define NNODES 50000
#define NEDGES 500000
#define ETOT   (NEDGES + NNODES)
#define DIN    128
#define CH     256
#define SLOPE  0.2f

typedef __attribute__((ext_vector_type(8))) short short8;
typedef __attribute__((ext_vector_type(4))) float f32x4;

static __device__ __forceinline__ float wave_reduce_max(float v) {
#pragma unroll
  for (int off = 32; off > 0; off >>= 1) v = fmaxf(v, __shfl_xor(v, off));
  return v;
}
static __device__ __forceinline__ float wave_reduce_sum(float v) {
#pragma unroll
  for (int off = 32; off > 0; off >>= 1) v += __shfl_xor(v, off);
  return v;
}

static __device__ __forceinline__ unsigned short f2bf(float f) {
  unsigned int u = __float_as_uint(f);
  unsigned int r = (u + 0x7fffu + ((u >> 16) & 1u)) >> 16;
  return (unsigned short)r;
}

// ---------------- CSR build (dst-sorted) ----------------
__global__ void degree_kernel(const int* __restrict__ ei, int* __restrict__ deg) {
  int e = blockIdx.x * blockDim.x + threadIdx.x;
  if (e >= ETOT) return;
  int dst = (e < NEDGES) ? ei[NEDGES + e] : (e - NEDGES);
  atomicAdd(&deg[dst], 1);
}

__global__ void scan_kernel(const int* __restrict__ deg, int* __restrict__ rowptr,
                            int* __restrict__ cursor) {
  __shared__ int buf[1024];
  __shared__ int carry_s;
  int tid = threadIdx.x;
  if (tid == 0) carry_s = 0;
  __syncthreads();
  for (int base = 0; base < NNODES; base += 1024) {
    int i = base + tid;
    int v = (i < NNODES) ? deg[i] : 0;
    buf[tid] = v;
    __syncthreads();
    for (int off = 1; off < 1024; off <<= 1) {
      int t = (tid >= off) ? buf[tid - off] : 0;
      __syncthreads();
      buf[tid] += t;
      __syncthreads();
    }
    int incl  = buf[tid];
    int total = buf[1023];
    int carry = carry_s;
    int excl  = carry + incl - v;
    if (i < NNODES) { rowptr[i] = excl; cursor[i] = excl; }
    __syncthreads();
    if (tid == 0) carry_s = carry + total;
    __syncthreads();
  }
  if (tid == 0) rowptr[NNODES] = carry_s;
}

__global__ void scatter_kernel(const int* __restrict__ ei, int* __restrict__ cursor,
                               int* __restrict__ csr_src) {
  int e = blockIdx.x * blockDim.x + threadIdx.x;
  if (e >= ETOT) return;
  int src, dst;
  if (e < NEDGES) { src = ei[e]; dst = ei[NEDGES + e]; }
  else            { src = e - NEDGES; dst = src; }
  int slot = atomicAdd(&cursor[dst], 1);
  csr_src[slot] = src;
}

// ---------------- cast helpers ----------------
// contiguous fp32 -> bf16 (n divisible by 4)
__global__ void cast_f32_bf16(const float* __restrict__ in,
                              unsigned short* __restrict__ outp, int n4) {
  int i = blockIdx.x * blockDim.x + threadIdx.x;
  if (i >= n4) return;
  float4 v = *(const float4*)(in + (size_t)i * 4);
  ushort4 o;
  o.x = f2bf(v.x); o.y = f2bf(v.y); o.z = f2bf(v.z); o.w = f2bf(v.w);
  *(ushort4*)(outp + (size_t)i * 4) = o;
}

// strided: out[n][0..255] (ld 512) -> packed bf16 [n][256]
__global__ void cast_x2(const float* __restrict__ src, unsigned short* __restrict__ x2) {
  int i = blockIdx.x * blockDim.x + threadIdx.x;  // 50000*64 threads
  if (i >= NNODES * 64) return;
  int row = i >> 6;
  int c4 = (i & 63) * 4;
  float4 v = *(const float4*)(src + (size_t)row * 512 + c4);
  ushort4 o;
  o.x = f2bf(v.x); o.y = f2bf(v.y); o.z = f2bf(v.z); o.w = f2bf(v.w);
  *(ushort4*)(x2 + (size_t)row * CH + c4) = o;
}

// ---------------- bf16 MFMA GEMM: H[m][c] = sum_k X[m][k]*W[c][k] ----------------
// block tile 128x128, 4 waves each 64x64 (4x4 of 16x16x32 MFMA), BK=64
#define TM 128
#define TN 128
#define TK 64
#define LDA (TK + 8)   // 72 elements -> even bank distribution for b128 reads

__global__ __launch_bounds__(256) void gemm_bf16(
    const unsigned short* __restrict__ X, int ldx,
    const unsigned short* __restrict__ W, int K,
    float* __restrict__ Hout, int M) {
  __shared__ short As[TM * LDA];
  __shared__ short Bs[TN * LDA];
  int bm = blockIdx.y * TM;
  int bn = blockIdx.x * TN;
  int tid = threadIdx.x;
  int wid = tid >> 6;
  int lane = tid & 63;
  int wm = (wid & 1) * 64;
  int wn = (wid >> 1) * 64;
  int lrow = lane & 15;
  int lk8 = (lane >> 4) * 8;

  int srow = tid >> 3;          // 0..31
  int skoff = (tid & 7) * 8;    // 0..56

  f32x4 acc[4][4] = {};

  for (int k0 = 0; k0 < K; k0 += TK) {
#pragma unroll
    for (int i = 0; i < 4; i++) {
      int r = srow + 32 * i;
      int gm = bm + r;
      short8 v = {};
      if (gm < M) v = *(const short8*)(X + (size_t)gm * ldx + k0 + skoff);
      *(short8*)(&As[r * LDA + skoff]) = v;
      short8 w = *(const short8*)(W + (size_t)(bn + r) * K + k0 + skoff);
      *(short8*)(&Bs[r * LDA + skoff]) = w;
    }
    __syncthreads();
#pragma unroll
    for (int kk = 0; kk < TK; kk += 32) {
      short8 a[4], b[4];
#pragma unroll
      for (int mi = 0; mi < 4; mi++)
        a[mi] = *(const short8*)(&As[(wm + mi * 16 + lrow) * LDA + kk + lk8]);
#pragma unroll
      for (int ni = 0; ni < 4; ni++)
        b[ni] = *(const short8*)(&Bs[(wn + ni * 16 + lrow) * LDA + kk + lk8]);
#pragma unroll
      for (int mi = 0; mi < 4; mi++)
#pragma unroll
        for (int ni = 0; ni < 4; ni++)
          acc[mi][ni] = __builtin_amdgcn_mfma_f32_16x16x32_bf16(a[mi], b[ni], acc[mi][ni], 0, 0, 0);
    }
    __syncthreads();
  }

  // C/D layout: col = lane&15, row = (lane>>4)*4 + reg
  int crow = (lane >> 4) * 4;
  int ccol = lane & 15;
#pragma unroll
  for (int mi = 0; mi < 4; mi++) {
#pragma unroll
    for (int ni = 0; ni < 4; ni++) {
#pragma unroll
      for (int r = 0; r < 4; r++) {
        int gm = bm + wm + mi * 16 + crow + r;
        if (gm < M) Hout[(size_t)gm * CH + bn + wn + ni * 16 + ccol] = acc[mi][ni][r];
      }
    }
  }
}

// ---------------- per-node attention scores ----------------
__global__ __launch_bounds__(64) void score_kernel(const float* __restrict__ Hm,
                                                   const float* __restrict__ a_src,
                                                   const float* __restrict__ a_dst,
                                                   float* __restrict__ eS,
                                                   float* __restrict__ eD) {
  int n = blockIdx.x;
  int lane = threadIdx.x;
  float4 h  = *(const float4*)(Hm + (size_t)n * CH + lane * 4);
  float4 as = *(const float4*)(a_src + lane * 4);
  float4 ad = *(const float4*)(a_dst + lane * 4);
  float s = h.x * as.x + h.y * as.y + h.z * as.z + h.w * as.w;
  float d = h.x * ad.x + h.y * ad.y + h.z * ad.z + h.w * ad.w;
  s = wave_reduce_sum(s);
  d = wave_reduce_sum(d);
  if (lane == 0) { eS[n] = s; eD[n] = d; }
}

// ---------------- per-node softmax + aggregate (+bias, +ReLU) ----------------
__global__ __launch_bounds__(64) void aggregate_kernel(
    const float* __restrict__ Hm, const float* __restrict__ eS,
    const float* __restrict__ eD, const int* __restrict__ rowptr,
    const int* __restrict__ csr_src, const float* __restrict__ bias,
    float* __restrict__ out, int outOffset) {
  int n = blockIdx.x;
  int lane = threadIdx.x;
  int beg = rowptr[n], end = rowptr[n + 1];
  float ed = eD[n];

  float m = -1e30f;
  for (int k = beg + lane; k < end; k += 64) {
    float e = eS[csr_src[k]] + ed;
    e = (e >= 0.f) ? e : SLOPE * e;
    m = fmaxf(m, e);
  }
  m = wave_reduce_max(m);

  float dsum = 0.f;
  for (int k = beg + lane; k < end; k += 64) {
    float e = eS[csr_src[k]] + ed;
    e = (e >= 0.f) ? e : SLOPE * e;
    dsum += __expf(e - m);
  }
  dsum = wave_reduce_sum(dsum) + 1e-16f;
  float inv = 1.f / dsum;

  float4 acc = make_float4(0.f, 0.f, 0.f, 0.f);
  for (int k = beg; k < end; k++) {
    int s = csr_src[k];
    float e = eS[s] + ed;
    e = (e >= 0.f) ? e : SLOPE * e;
    float alpha = __expf(e - m) * inv;
    float4 h = *(const float4*)(Hm + (size_t)s * CH + lane * 4);
    acc.x += alpha * h.x; acc.y += alpha * h.y;
    acc.z += alpha * h.z; acc.w += alpha * h.w;
  }
  float4 b = *(const float4*)(bias + lane * 4);
  float4 o;
  o.x = fmaxf(acc.x + b.x, 0.f);
  o.y = fmaxf(acc.y + b.y, 0.f);
  o.z = fmaxf(acc.z + b.z, 0.f);
  o.w = fmaxf(acc.w + b.w, 0.f);
  *(float4*)(out + (size_t)n * 512 + outOffset + lane * 4) = o;
}

extern "C" void kernel_launch(void* const* d_in, const int* in_sizes, int n_in,
                              void* d_out, int out_size, void* d_ws, size_t ws_size,
                              hipStream_t stream) {
  const float* x   = (const float*)d_in[0];
  const int*   ei  = (const int*)d_in[1];
  const float* W1  = (const float*)d_in[2];
  const float* a1s = (const float*)d_in[3];
  const float* a1d = (const float*)d_in[4];
  const float* b1  = (const float*)d_in[5];
  const float* W2  = (const float*)d_in[6];
  const float* a2s = (const float*)d_in[7];
  const float* a2d = (const float*)d_in[8];
  const float* b2  = (const float*)d_in[9];
  float* out = (float*)d_out;

  char* ws = (char*)d_ws;
  size_t off = 0;
  auto alloc = [&](size_t bytes) -> void* {
    void* p = ws + off;
    off = (off + bytes + 255) & ~(size_t)255;
    return p;
  };
  float*          Hm     = (float*)alloc(sizeof(float) * (size_t)NNODES * CH);
  unsigned short* Xb     = (unsigned short*)alloc(sizeof(short) * (size_t)NNODES * CH);
  unsigned short* Wb     = (unsigned short*)alloc(sizeof(short) * CH * CH);
  float*          eS     = (float*)alloc(sizeof(float) * NNODES);
  float*          eD     = (float*)alloc(sizeof(float) * NNODES);
  int*            rowptr = (int*)alloc(sizeof(int) * (NNODES + 1));
  int*            cursor = (int*)alloc(sizeof(int) * NNODES);
  int*            csrsrc = (int*)alloc(sizeof(int) * ETOT);
  int*            deg    = (int*)alloc(sizeof(int) * NNODES);

  // CSR build (edge list identical for both layers)
  hipMemsetAsync(deg, 0, sizeof(int) * NNODES, stream);
  degree_kernel<<<(ETOT + 255) / 256, 256, 0, stream>>>(ei, deg);
  scan_kernel<<<1, 1024, 0, stream>>>(deg, rowptr, cursor);
  scatter_kernel<<<(ETOT + 255) / 256, 256, 0, stream>>>(ei, cursor, csrsrc);

  dim3 gemm_grid(TN == 128 ? 2 : 1, (NNODES + TM - 1) / TM);

  // ---- layer 1 ----
  {
    int n4 = NNODES * DIN / 4;
    cast_f32_bf16<<<(n4 + 255) / 256, 256, 0, stream>>>(x, Xb, n4);
    int w4 = CH * DIN / 4;
    cast_f32_bf16<<<(w4 + 255) / 256, 256, 0, stream>>>(W1, Wb, w4);
  }
  gemm_bf16<<<gemm_grid, 256, 0, stream>>>(Xb, DIN, Wb, DIN, Hm, NNODES);
  score_kernel<<<NNODES, 64, 0, stream>>>(Hm, a1s, a1d, eS, eD);
  aggregate_kernel<<<NNODES, 64, 0, stream>>>(Hm, eS, eD, rowptr, csrsrc, b1, out, 0);

  // ---- layer 2 ----
  {
    int t = NNODES * 64;
    cast_x2<<<(t + 255) / 256, 256, 0, stream>>>(out, Xb);
    int w4 = CH * CH / 4;
    cast_f32_bf16<<<(w4 + 255) / 256, 256, 0, stream>>>(W2, Wb, w4);
  }
  gemm_bf16<<<gemm_grid, 256, 0, stream>>>(Xb, CH, Wb, CH, Hm, NNODES);
  score_kernel<<<NNODES, 64, 0, stream>>>(Hm, a2s, a2d, eS, eD);
  aggregate_kernel<<<NNODES, 64, 0, stream>>>(Hm, eS, eD, rowptr, csrsrc, b2, out, 256);
}

// Round 4
// 432.123 us; speedup vs baseline: 1.5067x; 1.2020x over previous
//
#include <hip/hip_runtime.h>
#include <hip/hip_bf16.h>
#include <math.h>

#define NNODES 50000
#define NEDGES 500000
#define ETOT   (NEDGES + NNODES)
#define DIN    128
#define CH     256
#define SLOPE  0.2f

#define SCAN_TILE 1024
#define NSCAN ((NNODES + SCAN_TILE - 1) / SCAN_TILE)   // 49

typedef __attribute__((ext_vector_type(8))) short short8;
typedef __attribute__((ext_vector_type(4))) float f32x4;

static __device__ __forceinline__ float wave_reduce_max(float v) {
#pragma unroll
  for (int off = 32; off > 0; off >>= 1) v = fmaxf(v, __shfl_xor(v, off));
  return v;
}
static __device__ __forceinline__ float wave_reduce_sum(float v) {
#pragma unroll
  for (int off = 32; off > 0; off >>= 1) v += __shfl_xor(v, off);
  return v;
}

static __device__ __forceinline__ unsigned short f2bf(float f) {
  unsigned int u = __float_as_uint(f);
  unsigned int r = (u + 0x7fffu + ((u >> 16) & 1u)) >> 16;
  return (unsigned short)r;
}

// ---------------- CSR build (dst-sorted) ----------------
__global__ void degree_kernel(const int* __restrict__ ei, int* __restrict__ deg) {
  int e = blockIdx.x * blockDim.x + threadIdx.x;
  if (e >= ETOT) return;
  int dst = (e < NEDGES) ? ei[NEDGES + e] : (e - NEDGES);
  atomicAdd(&deg[dst], 1);
}

// --- 3-phase multi-block exclusive scan of deg[0..NNODES) ---
// A: per-tile (1024 elems) sums
__global__ __launch_bounds__(256) void scan_blocksums(const int* __restrict__ deg,
                                                      int* __restrict__ bsums) {
  __shared__ int sdata[4];
  int b = blockIdx.x;
  int tid = threadIdx.x;
  int idx = b * SCAN_TILE + tid * 4;
  int s = 0;
  if (idx + 3 < NNODES) {
    int4 v = *(const int4*)(deg + idx);
    s = v.x + v.y + v.z + v.w;
  } else {
#pragma unroll
    for (int j = 0; j < 4; j++) if (idx + j < NNODES) s += deg[idx + j];
  }
#pragma unroll
  for (int off = 32; off > 0; off >>= 1) s += __shfl_xor(s, off);
  if ((tid & 63) == 0) sdata[tid >> 6] = s;
  __syncthreads();
  if (tid == 0) bsums[b] = sdata[0] + sdata[1] + sdata[2] + sdata[3];
}

// B: scan the NSCAN (=49) tile sums in one wave
__global__ __launch_bounds__(64) void scan_bsums(const int* __restrict__ bsums,
                                                 int* __restrict__ boffs,
                                                 int* __restrict__ rowptr) {
  int tid = threadIdx.x;
  int v = (tid < NSCAN) ? bsums[tid] : 0;
  int x = v;
#pragma unroll
  for (int off = 1; off < 64; off <<= 1) {
    int t = __shfl_up(x, off);
    if (tid >= off) x += t;
  }
  if (tid < NSCAN) boffs[tid] = x - v;       // exclusive tile offset
  if (tid == 63) rowptr[NNODES] = x;         // grand total (lanes >= NSCAN add 0)
}

// C: per-tile scan + tile offset -> rowptr/cursor
__global__ __launch_bounds__(256) void scan_final(const int* __restrict__ deg,
                                                  const int* __restrict__ boffs,
                                                  int* __restrict__ rowptr,
                                                  int* __restrict__ cursor) {
  __shared__ int wsums[4];
  int b = blockIdx.x;
  int tid = threadIdx.x;
  int lane = tid & 63;
  int base = b * SCAN_TILE + tid * 4;
  int d[4];
  int s = 0;
#pragma unroll
  for (int j = 0; j < 4; j++) {
    d[j] = (base + j < NNODES) ? deg[base + j] : 0;
    s += d[j];
  }
  int x = s;
#pragma unroll
  for (int off = 1; off < 64; off <<= 1) {
    int t = __shfl_up(x, off);
    if (lane >= off) x += t;
  }
  if (lane == 63) wsums[tid >> 6] = x;
  __syncthreads();
  int woff = 0;
  int w = tid >> 6;
  for (int i = 0; i < w; i++) woff += wsums[i];
  int excl = boffs[b] + woff + (x - s);
#pragma unroll
  for (int j = 0; j < 4; j++) {
    if (base + j < NNODES) { rowptr[base + j] = excl; cursor[base + j] = excl; }
    excl += d[j];
  }
}

__global__ void scatter_kernel(const int* __restrict__ ei, int* __restrict__ cursor,
                               int* __restrict__ csr_src) {
  int e = blockIdx.x * blockDim.x + threadIdx.x;
  if (e >= ETOT) return;
  int src, dst;
  if (e < NEDGES) { src = ei[e]; dst = ei[NEDGES + e]; }
  else            { src = e - NEDGES; dst = src; }
  int slot = atomicAdd(&cursor[dst], 1);
  csr_src[slot] = src;
}

// ---------------- cast helpers ----------------
__global__ void cast_f32_bf16(const float* __restrict__ in,
                              unsigned short* __restrict__ outp, int n4) {
  int i = blockIdx.x * blockDim.x + threadIdx.x;
  if (i >= n4) return;
  float4 v = *(const float4*)(in + (size_t)i * 4);
  ushort4 o;
  o.x = f2bf(v.x); o.y = f2bf(v.y); o.z = f2bf(v.z); o.w = f2bf(v.w);
  *(ushort4*)(outp + (size_t)i * 4) = o;
}

__global__ void cast_x2(const float* __restrict__ src, unsigned short* __restrict__ x2) {
  int i = blockIdx.x * blockDim.x + threadIdx.x;  // 50000*64 threads
  if (i >= NNODES * 64) return;
  int row = i >> 6;
  int c4 = (i & 63) * 4;
  float4 v = *(const float4*)(src + (size_t)row * 512 + c4);
  ushort4 o;
  o.x = f2bf(v.x); o.y = f2bf(v.y); o.z = f2bf(v.z); o.w = f2bf(v.w);
  *(ushort4*)(x2 + (size_t)row * CH + c4) = o;
}

// ---------------- bf16 MFMA GEMM: H[m][c] = sum_k X[m][k]*W[c][k] ----------------
#define TM 128
#define TN 128
#define TK 64
#define LDA (TK + 8)

__global__ __launch_bounds__(256) void gemm_bf16(
    const unsigned short* __restrict__ X, int ldx,
    const unsigned short* __restrict__ W, int K,
    float* __restrict__ Hout, int M) {
  __shared__ short As[TM * LDA];
  __shared__ short Bs[TN * LDA];
  int bm = blockIdx.y * TM;
  int bn = blockIdx.x * TN;
  int tid = threadIdx.x;
  int wid = tid >> 6;
  int lane = tid & 63;
  int wm = (wid & 1) * 64;
  int wn = (wid >> 1) * 64;
  int lrow = lane & 15;
  int lk8 = (lane >> 4) * 8;

  int srow = tid >> 3;
  int skoff = (tid & 7) * 8;

  f32x4 acc[4][4] = {};

  for (int k0 = 0; k0 < K; k0 += TK) {
#pragma unroll
    for (int i = 0; i < 4; i++) {
      int r = srow + 32 * i;
      int gm = bm + r;
      short8 v = {};
      if (gm < M) v = *(const short8*)(X + (size_t)gm * ldx + k0 + skoff);
      *(short8*)(&As[r * LDA + skoff]) = v;
      short8 w = *(const short8*)(W + (size_t)(bn + r) * K + k0 + skoff);
      *(short8*)(&Bs[r * LDA + skoff]) = w;
    }
    __syncthreads();
#pragma unroll
    for (int kk = 0; kk < TK; kk += 32) {
      short8 a[4], b[4];
#pragma unroll
      for (int mi = 0; mi < 4; mi++)
        a[mi] = *(const short8*)(&As[(wm + mi * 16 + lrow) * LDA + kk + lk8]);
#pragma unroll
      for (int ni = 0; ni < 4; ni++)
        b[ni] = *(const short8*)(&Bs[(wn + ni * 16 + lrow) * LDA + kk + lk8]);
#pragma unroll
      for (int mi = 0; mi < 4; mi++)
#pragma unroll
        for (int ni = 0; ni < 4; ni++)
          acc[mi][ni] = __builtin_amdgcn_mfma_f32_16x16x32_bf16(a[mi], b[ni], acc[mi][ni], 0, 0, 0);
    }
    __syncthreads();
  }

  int crow = (lane >> 4) * 4;
  int ccol = lane & 15;
#pragma unroll
  for (int mi = 0; mi < 4; mi++) {
#pragma unroll
    for (int ni = 0; ni < 4; ni++) {
#pragma unroll
      for (int r = 0; r < 4; r++) {
        int gm = bm + wm + mi * 16 + crow + r;
        if (gm < M) Hout[(size_t)gm * CH + bn + wn + ni * 16 + ccol] = acc[mi][ni][r];
      }
    }
  }
}

// ---------------- per-node attention scores ----------------
__global__ __launch_bounds__(64) void score_kernel(const float* __restrict__ Hm,
                                                   const float* __restrict__ a_src,
                                                   const float* __restrict__ a_dst,
                                                   float* __restrict__ eS,
                                                   float* __restrict__ eD) {
  int n = blockIdx.x;
  int lane = threadIdx.x;
  float4 h  = *(const float4*)(Hm + (size_t)n * CH + lane * 4);
  float4 as = *(const float4*)(a_src + lane * 4);
  float4 ad = *(const float4*)(a_dst + lane * 4);
  float s = h.x * as.x + h.y * as.y + h.z * as.z + h.w * as.w;
  float d = h.x * ad.x + h.y * ad.y + h.z * ad.z + h.w * ad.w;
  s = wave_reduce_sum(s);
  d = wave_reduce_sum(d);
  if (lane == 0) { eS[n] = s; eD[n] = d; }
}

// ---------------- per-node softmax + aggregate (+bias, +ReLU) ----------------
__global__ __launch_bounds__(64) void aggregate_kernel(
    const float* __restrict__ Hm, const float* __restrict__ eS,
    const float* __restrict__ eD, const int* __restrict__ rowptr,
    const int* __restrict__ csr_src, const float* __restrict__ bias,
    float* __restrict__ out, int outOffset) {
  int n = blockIdx.x;
  int lane = threadIdx.x;
  int beg = rowptr[n], end = rowptr[n + 1];
  float ed = eD[n];

  float m = -1e30f;
  for (int k = beg + lane; k < end; k += 64) {
    float e = eS[csr_src[k]] + ed;
    e = (e >= 0.f) ? e : SLOPE * e;
    m = fmaxf(m, e);
  }
  m = wave_reduce_max(m);

  float dsum = 0.f;
  for (int k = beg + lane; k < end; k += 64) {
    float e = eS[csr_src[k]] + ed;
    e = (e >= 0.f) ? e : SLOPE * e;
    dsum += __expf(e - m);
  }
  dsum = wave_reduce_sum(dsum) + 1e-16f;
  float inv = 1.f / dsum;

  float4 acc = make_float4(0.f, 0.f, 0.f, 0.f);
  for (int k = beg; k < end; k++) {
    int s = csr_src[k];
    float e = eS[s] + ed;
    e = (e >= 0.f) ? e : SLOPE * e;
    float alpha = __expf(e - m) * inv;
    float4 h = *(const float4*)(Hm + (size_t)s * CH + lane * 4);
    acc.x += alpha * h.x; acc.y += alpha * h.y;
    acc.z += alpha * h.z; acc.w += alpha * h.w;
  }
  float4 b = *(const float4*)(bias + lane * 4);
  float4 o;
  o.x = fmaxf(acc.x + b.x, 0.f);
  o.y = fmaxf(acc.y + b.y, 0.f);
  o.z = fmaxf(acc.z + b.z, 0.f);
  o.w = fmaxf(acc.w + b.w, 0.f);
  *(float4*)(out + (size_t)n * 512 + outOffset + lane * 4) = o;
}

extern "C" void kernel_launch(void* const* d_in, const int* in_sizes, int n_in,
                              void* d_out, int out_size, void* d_ws, size_t ws_size,
                              hipStream_t stream) {
  const float* x   = (const float*)d_in[0];
  const int*   ei  = (const int*)d_in[1];
  const float* W1  = (const float*)d_in[2];
  const float* a1s = (const float*)d_in[3];
  const float* a1d = (const float*)d_in[4];
  const float* b1  = (const float*)d_in[5];
  const float* W2  = (const float*)d_in[6];
  const float* a2s = (const float*)d_in[7];
  const float* a2d = (const float*)d_in[8];
  const float* b2  = (const float*)d_in[9];
  float* out = (float*)d_out;

  char* ws = (char*)d_ws;
  size_t off = 0;
  auto alloc = [&](size_t bytes) -> void* {
    void* p = ws + off;
    off = (off + bytes + 255) & ~(size_t)255;
    return p;
  };
  float*          Hm     = (float*)alloc(sizeof(float) * (size_t)NNODES * CH);
  unsigned short* Xb     = (unsigned short*)alloc(sizeof(short) * (size_t)NNODES * CH);
  unsigned short* Wb     = (unsigned short*)alloc(sizeof(short) * CH * CH);
  float*          eS     = (float*)alloc(sizeof(float) * NNODES);
  float*          eD     = (float*)alloc(sizeof(float) * NNODES);
  int*            rowptr = (int*)alloc(sizeof(int) * (NNODES + 1));
  int*            cursor = (int*)alloc(sizeof(int) * NNODES);
  int*            csrsrc = (int*)alloc(sizeof(int) * ETOT);
  int*            deg    = (int*)alloc(sizeof(int) * NNODES);
  int*            bsums  = (int*)alloc(sizeof(int) * NSCAN);
  int*            boffs  = (int*)alloc(sizeof(int) * NSCAN);

  // CSR build (edge list identical for both layers)
  hipMemsetAsync(deg, 0, sizeof(int) * NNODES, stream);
  degree_kernel<<<(ETOT + 255) / 256, 256, 0, stream>>>(ei, deg);
  scan_blocksums<<<NSCAN, 256, 0, stream>>>(deg, bsums);
  scan_bsums<<<1, 64, 0, stream>>>(bsums, boffs, rowptr);
  scan_final<<<NSCAN, 256, 0, stream>>>(deg, boffs, rowptr, cursor);
  scatter_kernel<<<(ETOT + 255) / 256, 256, 0, stream>>>(ei, cursor, csrsrc);

  dim3 gemm_grid(2, (NNODES + TM - 1) / TM);

  // ---- layer 1 ----
  {
    int n4 = NNODES * DIN / 4;
    cast_f32_bf16<<<(n4 + 255) / 256, 256, 0, stream>>>(x, Xb, n4);
    int w4 = CH * DIN / 4;
    cast_f32_bf16<<<(w4 + 255) / 256, 256, 0, stream>>>(W1, Wb, w4);
  }
  gemm_bf16<<<gemm_grid, 256, 0, stream>>>(Xb, DIN, Wb, DIN, Hm, NNODES);
  score_kernel<<<NNODES, 64, 0, stream>>>(Hm, a1s, a1d, eS, eD);
  aggregate_kernel<<<NNODES, 64, 0, stream>>>(Hm, eS, eD, rowptr, csrsrc, b1, out, 0);

  // ---- layer 2 ----
  {
    int t = NNODES * 64;
    cast_x2<<<(t + 255) / 256, 256, 0, stream>>>(out, Xb);
    int w4 = CH * CH / 4;
    cast_f32_bf16<<<(w4 + 255) / 256, 256, 0, stream>>>(W2, Wb, w4);
  }
  gemm_bf16<<<gemm_grid, 256, 0, stream>>>(Xb, CH, Wb, CH, Hm, NNODES);
  score_kernel<<<NNODES, 64, 0, stream>>>(Hm, a2s, a2d, eS, eD);
  aggregate_kernel<<<NNODES, 64, 0, stream>>>(Hm, eS, eD, rowptr, csrsrc, b2, out, 256);
}

// Round 5
// 407.802 us; speedup vs baseline: 1.5965x; 1.0596x over previous
//
#include <hip/hip_runtime.h>
#include <hip/hip_bf16.h>
#include <math.h>

#define NNODES 50000
#define NEDGES 500000
#define ETOT   (NEDGES + NNODES)
#define DIN    128
#define CH     256
#define SLOPE  0.2f

#define SCAN_TILE 1024
#define NSCAN ((NNODES + SCAN_TILE - 1) / SCAN_TILE)   // 49

typedef __attribute__((ext_vector_type(8))) short short8;
typedef __attribute__((ext_vector_type(4))) float f32x4;

static __device__ __forceinline__ float wave_reduce_max(float v) {
#pragma unroll
  for (int off = 32; off > 0; off >>= 1) v = fmaxf(v, __shfl_xor(v, off));
  return v;
}
static __device__ __forceinline__ float wave_reduce_sum(float v) {
#pragma unroll
  for (int off = 32; off > 0; off >>= 1) v += __shfl_xor(v, off);
  return v;
}

static __device__ __forceinline__ unsigned short f2bf(float f) {
  unsigned int u = __float_as_uint(f);
  unsigned int r = (u + 0x7fffu + ((u >> 16) & 1u)) >> 16;
  return (unsigned short)r;
}
static __device__ __forceinline__ float bf2f(unsigned short u) {
  return __uint_as_float(((unsigned int)u) << 16);
}

// ---------------- CSR build (dst-sorted) ----------------
__global__ void degree_kernel(const int* __restrict__ ei, int* __restrict__ deg) {
  int e = blockIdx.x * blockDim.x + threadIdx.x;
  if (e >= ETOT) return;
  int dst = (e < NEDGES) ? ei[NEDGES + e] : (e - NEDGES);
  atomicAdd(&deg[dst], 1);
}

__global__ __launch_bounds__(256) void scan_blocksums(const int* __restrict__ deg,
                                                      int* __restrict__ bsums) {
  __shared__ int sdata[4];
  int b = blockIdx.x;
  int tid = threadIdx.x;
  int idx = b * SCAN_TILE + tid * 4;
  int s = 0;
  if (idx + 3 < NNODES) {
    int4 v = *(const int4*)(deg + idx);
    s = v.x + v.y + v.z + v.w;
  } else {
#pragma unroll
    for (int j = 0; j < 4; j++) if (idx + j < NNODES) s += deg[idx + j];
  }
#pragma unroll
  for (int off = 32; off > 0; off >>= 1) s += __shfl_xor(s, off);
  if ((tid & 63) == 0) sdata[tid >> 6] = s;
  __syncthreads();
  if (tid == 0) bsums[b] = sdata[0] + sdata[1] + sdata[2] + sdata[3];
}

__global__ __launch_bounds__(64) void scan_bsums(const int* __restrict__ bsums,
                                                 int* __restrict__ boffs,
                                                 int* __restrict__ rowptr) {
  int tid = threadIdx.x;
  int v = (tid < NSCAN) ? bsums[tid] : 0;
  int x = v;
#pragma unroll
  for (int off = 1; off < 64; off <<= 1) {
    int t = __shfl_up(x, off);
    if (tid >= off) x += t;
  }
  if (tid < NSCAN) boffs[tid] = x - v;
  if (tid == 63) rowptr[NNODES] = x;
}

__global__ __launch_bounds__(256) void scan_final(const int* __restrict__ deg,
                                                  const int* __restrict__ boffs,
                                                  int* __restrict__ rowptr,
                                                  int* __restrict__ cursor) {
  __shared__ int wsums[4];
  int b = blockIdx.x;
  int tid = threadIdx.x;
  int lane = tid & 63;
  int base = b * SCAN_TILE + tid * 4;
  int d[4];
  int s = 0;
#pragma unroll
  for (int j = 0; j < 4; j++) {
    d[j] = (base + j < NNODES) ? deg[base + j] : 0;
    s += d[j];
  }
  int x = s;
#pragma unroll
  for (int off = 1; off < 64; off <<= 1) {
    int t = __shfl_up(x, off);
    if (lane >= off) x += t;
  }
  if (lane == 63) wsums[tid >> 6] = x;
  __syncthreads();
  int woff = 0;
  int w = tid >> 6;
  for (int i = 0; i < w; i++) woff += wsums[i];
  int excl = boffs[b] + woff + (x - s);
#pragma unroll
  for (int j = 0; j < 4; j++) {
    if (base + j < NNODES) { rowptr[base + j] = excl; cursor[base + j] = excl; }
    excl += d[j];
  }
}

__global__ void scatter_kernel(const int* __restrict__ ei, int* __restrict__ cursor,
                               int* __restrict__ csr_src) {
  int e = blockIdx.x * blockDim.x + threadIdx.x;
  if (e >= ETOT) return;
  int src, dst;
  if (e < NEDGES) { src = ei[e]; dst = ei[NEDGES + e]; }
  else            { src = e - NEDGES; dst = src; }
  int slot = atomicAdd(&cursor[dst], 1);
  csr_src[slot] = src;
}

// ---------------- cast helper ----------------
__global__ void cast_f32_bf16(const float* __restrict__ in,
                              unsigned short* __restrict__ outp, int n4) {
  int i = blockIdx.x * blockDim.x + threadIdx.x;
  if (i >= n4) return;
  float4 v = *(const float4*)(in + (size_t)i * 4);
  ushort4 o;
  o.x = f2bf(v.x); o.y = f2bf(v.y); o.z = f2bf(v.z); o.w = f2bf(v.w);
  *(ushort4*)(outp + (size_t)i * 4) = o;
}

// ---------------- bf16 MFMA GEMM: Hb[m][c] = bf16(sum_k X[m][k]*W[c][k]) ----------------
#define TM 128
#define TN 128
#define TK 64
#define LDA (TK + 8)

__global__ __launch_bounds__(256) void gemm_bf16(
    const unsigned short* __restrict__ X, int ldx,
    const unsigned short* __restrict__ W, int K,
    unsigned short* __restrict__ Hout, int M) {
  __shared__ short As[TM * LDA];
  __shared__ short Bs[TN * LDA];
  int bm = blockIdx.y * TM;
  int bn = blockIdx.x * TN;
  int tid = threadIdx.x;
  int wid = tid >> 6;
  int lane = tid & 63;
  int wm = (wid & 1) * 64;
  int wn = (wid >> 1) * 64;
  int lrow = lane & 15;
  int lk8 = (lane >> 4) * 8;

  int srow = tid >> 3;
  int skoff = (tid & 7) * 8;

  f32x4 acc[4][4] = {};

  for (int k0 = 0; k0 < K; k0 += TK) {
#pragma unroll
    for (int i = 0; i < 4; i++) {
      int r = srow + 32 * i;
      int gm = bm + r;
      short8 v = {};
      if (gm < M) v = *(const short8*)(X + (size_t)gm * ldx + k0 + skoff);
      *(short8*)(&As[r * LDA + skoff]) = v;
      short8 w = *(const short8*)(W + (size_t)(bn + r) * K + k0 + skoff);
      *(short8*)(&Bs[r * LDA + skoff]) = w;
    }
    __syncthreads();
#pragma unroll
    for (int kk = 0; kk < TK; kk += 32) {
      short8 a[4], b[4];
#pragma unroll
      for (int mi = 0; mi < 4; mi++)
        a[mi] = *(const short8*)(&As[(wm + mi * 16 + lrow) * LDA + kk + lk8]);
#pragma unroll
      for (int ni = 0; ni < 4; ni++)
        b[ni] = *(const short8*)(&Bs[(wn + ni * 16 + lrow) * LDA + kk + lk8]);
#pragma unroll
      for (int mi = 0; mi < 4; mi++)
#pragma unroll
        for (int ni = 0; ni < 4; ni++)
          acc[mi][ni] = __builtin_amdgcn_mfma_f32_16x16x32_bf16(a[mi], b[ni], acc[mi][ni], 0, 0, 0);
    }
    __syncthreads();
  }

  int crow = (lane >> 4) * 4;
  int ccol = lane & 15;
#pragma unroll
  for (int mi = 0; mi < 4; mi++) {
#pragma unroll
    for (int ni = 0; ni < 4; ni++) {
#pragma unroll
      for (int r = 0; r < 4; r++) {
        int gm = bm + wm + mi * 16 + crow + r;
        if (gm < M)
          Hout[(size_t)gm * CH + bn + wn + ni * 16 + ccol] = f2bf(acc[mi][ni][r]);
      }
    }
  }
}

// ---------------- per-node attention scores (4 nodes / 256-thr block) ----------------
__global__ __launch_bounds__(256) void score_kernel(const unsigned short* __restrict__ Hmb,
                                                    const float* __restrict__ a_src,
                                                    const float* __restrict__ a_dst,
                                                    float* __restrict__ eS,
                                                    float* __restrict__ eD) {
  int n = blockIdx.x * 4 + (threadIdx.x >> 6);
  if (n >= NNODES) return;
  int lane = threadIdx.x & 63;
  ushort4 hu = *(const ushort4*)(Hmb + (size_t)n * CH + lane * 4);
  float4 as = *(const float4*)(a_src + lane * 4);
  float4 ad = *(const float4*)(a_dst + lane * 4);
  float h0 = bf2f(hu.x), h1 = bf2f(hu.y), h2 = bf2f(hu.z), h3 = bf2f(hu.w);
  float s = h0 * as.x + h1 * as.y + h2 * as.z + h3 * as.w;
  float d = h0 * ad.x + h1 * ad.y + h2 * ad.z + h3 * ad.w;
  s = wave_reduce_sum(s);
  d = wave_reduce_sum(d);
  if (lane == 0) { eS[n] = s; eD[n] = d; }
}

// ---------------- per-node softmax + aggregate (+bias, +ReLU) ----------------
// xout != nullptr: also write packed bf16 copy (layer-2 GEMM input)
__global__ __launch_bounds__(256) void aggregate_kernel(
    const unsigned short* __restrict__ Hmb, const float* __restrict__ eS,
    const float* __restrict__ eD, const int* __restrict__ rowptr,
    const int* __restrict__ csr_src, const float* __restrict__ bias,
    float* __restrict__ out, int outOffset, unsigned short* __restrict__ xout) {
  int n = blockIdx.x * 4 + (threadIdx.x >> 6);
  if (n >= NNODES) return;
  int lane = threadIdx.x & 63;
  int beg = rowptr[n], end = rowptr[n + 1];
  float ed = eD[n];

  float m = -1e30f;
  for (int k = beg + lane; k < end; k += 64) {
    float e = eS[csr_src[k]] + ed;
    e = (e >= 0.f) ? e : SLOPE * e;
    m = fmaxf(m, e);
  }
  m = wave_reduce_max(m);

  float dsum = 0.f;
  for (int k = beg + lane; k < end; k += 64) {
    float e = eS[csr_src[k]] + ed;
    e = (e >= 0.f) ? e : SLOPE * e;
    dsum += __expf(e - m);
  }
  dsum = wave_reduce_sum(dsum) + 1e-16f;
  float inv = 1.f / dsum;

  float4 acc = make_float4(0.f, 0.f, 0.f, 0.f);
  for (int k = beg; k < end; k++) {
    int s = csr_src[k];
    float e = eS[s] + ed;
    e = (e >= 0.f) ? e : SLOPE * e;
    float alpha = __expf(e - m) * inv;
    ushort4 hu = *(const ushort4*)(Hmb + (size_t)s * CH + lane * 4);
    acc.x += alpha * bf2f(hu.x); acc.y += alpha * bf2f(hu.y);
    acc.z += alpha * bf2f(hu.z); acc.w += alpha * bf2f(hu.w);
  }
  float4 b = *(const float4*)(bias + lane * 4);
  float4 o;
  o.x = fmaxf(acc.x + b.x, 0.f);
  o.y = fmaxf(acc.y + b.y, 0.f);
  o.z = fmaxf(acc.z + b.z, 0.f);
  o.w = fmaxf(acc.w + b.w, 0.f);
  *(float4*)(out + (size_t)n * 512 + outOffset + lane * 4) = o;
  if (xout) {
    ushort4 ob;
    ob.x = f2bf(o.x); ob.y = f2bf(o.y); ob.z = f2bf(o.z); ob.w = f2bf(o.w);
    *(ushort4*)(xout + (size_t)n * CH + lane * 4) = ob;
  }
}

extern "C" void kernel_launch(void* const* d_in, const int* in_sizes, int n_in,
                              void* d_out, int out_size, void* d_ws, size_t ws_size,
                              hipStream_t stream) {
  const float* x   = (const float*)d_in[0];
  const int*   ei  = (const int*)d_in[1];
  const float* W1  = (const float*)d_in[2];
  const float* a1s = (const float*)d_in[3];
  const float* a1d = (const float*)d_in[4];
  const float* b1  = (const float*)d_in[5];
  const float* W2  = (const float*)d_in[6];
  const float* a2s = (const float*)d_in[7];
  const float* a2d = (const float*)d_in[8];
  const float* b2  = (const float*)d_in[9];
  float* out = (float*)d_out;

  char* ws = (char*)d_ws;
  size_t off = 0;
  auto alloc = [&](size_t bytes) -> void* {
    void* p = ws + off;
    off = (off + bytes + 255) & ~(size_t)255;
    return p;
  };
  unsigned short* Hmb    = (unsigned short*)alloc(sizeof(short) * (size_t)NNODES * CH);
  unsigned short* Xb     = (unsigned short*)alloc(sizeof(short) * (size_t)NNODES * CH);
  unsigned short* Wb     = (unsigned short*)alloc(sizeof(short) * CH * CH);
  float*          eS     = (float*)alloc(sizeof(float) * NNODES);
  float*          eD     = (float*)alloc(sizeof(float) * NNODES);
  int*            rowptr = (int*)alloc(sizeof(int) * (NNODES + 1));
  int*            cursor = (int*)alloc(sizeof(int) * NNODES);
  int*            csrsrc = (int*)alloc(sizeof(int) * ETOT);
  int*            deg    = (int*)alloc(sizeof(int) * NNODES);
  int*            bsums  = (int*)alloc(sizeof(int) * NSCAN);
  int*            boffs  = (int*)alloc(sizeof(int) * NSCAN);

  // CSR build (edge list identical for both layers)
  hipMemsetAsync(deg, 0, sizeof(int) * NNODES, stream);
  degree_kernel<<<(ETOT + 255) / 256, 256, 0, stream>>>(ei, deg);
  scan_blocksums<<<NSCAN, 256, 0, stream>>>(deg, bsums);
  scan_bsums<<<1, 64, 0, stream>>>(bsums, boffs, rowptr);
  scan_final<<<NSCAN, 256, 0, stream>>>(deg, boffs, rowptr, cursor);
  scatter_kernel<<<(ETOT + 255) / 256, 256, 0, stream>>>(ei, cursor, csrsrc);

  dim3 gemm_grid(2, (NNODES + TM - 1) / TM);
  int nblk4 = (NNODES + 3) / 4;

  // ---- layer 1 ----
  {
    int n4 = NNODES * DIN / 4;
    cast_f32_bf16<<<(n4 + 255) / 256, 256, 0, stream>>>(x, Xb, n4);
    int w4 = CH * DIN / 4;
    cast_f32_bf16<<<(w4 + 255) / 256, 256, 0, stream>>>(W1, Wb, w4);
  }
  gemm_bf16<<<gemm_grid, 256, 0, stream>>>(Xb, DIN, Wb, DIN, Hmb, NNODES);
  score_kernel<<<nblk4, 256, 0, stream>>>(Hmb, a1s, a1d, eS, eD);
  aggregate_kernel<<<nblk4, 256, 0, stream>>>(Hmb, eS, eD, rowptr, csrsrc, b1, out, 0, Xb);

  // ---- layer 2 ----
  {
    int w4 = CH * CH / 4;
    cast_f32_bf16<<<(w4 + 255) / 256, 256, 0, stream>>>(W2, Wb, w4);
  }
  gemm_bf16<<<gemm_grid, 256, 0, stream>>>(Xb, CH, Wb, CH, Hmb, NNODES);
  score_kernel<<<nblk4, 256, 0, stream>>>(Hmb, a2s, a2d, eS, eD);
  aggregate_kernel<<<nblk4, 256, 0, stream>>>(Hmb, eS, eD, rowptr, csrsrc, b2, out, 256, (unsigned short*)nullptr);
}